// Round 4
// baseline (169.967 us; speedup 1.0000x reference)
//
#include <hip/hip_runtime.h>
#include <cstdint>
#include <cstddef>

#define BB 16
#define CC 256
#define NP 1024   // H*W

typedef __attribute__((ext_vector_type(8))) short bf16x8;
typedef __attribute__((ext_vector_type(4))) float f32x4;
typedef unsigned short u16;

__device__ __forceinline__ u16 f2bf(float f) {
    union { float f; uint32_t u; } v; v.f = f;
    uint32_t u = v.u;
    return (u16)((u + 0x7FFFu + ((u >> 16) & 1u)) >> 16);   // RNE
}

// ---------------- SE mean (blocks 0..4095) + weight convert (blocks 4096..4607) ----------------
__global__ __launch_bounds__(256)
void se_mean_conv_kernel(const float* __restrict__ x, float* __restrict__ s_mean,
                         const float* __restrict__ w1, u16* __restrict__ d1,
                         const float* __restrict__ w2, u16* __restrict__ d2) {
    int blk = blockIdx.x;
    int t = threadIdx.x;
    if (blk < BB * CC) {
        const float* p = x + (size_t)blk * NP;
        float4 v = *(const float4*)(p + t * 4);
        float s = (v.x + v.y) + (v.z + v.w);
#pragma unroll
        for (int off = 32; off; off >>= 1) s += __shfl_down(s, off, 64);
        __shared__ float red[4];
        if ((t & 63) == 0) red[t >> 6] = s;
        __syncthreads();
        if (t == 0) s_mean[blk] = (red[0] + red[1] + red[2] + red[3]) * (1.0f / NP);
    } else {
        int blk2 = blk - BB * CC;
        const float* src = (blk2 < 256) ? w1 : w2;
        u16* dst = (blk2 < 256) ? d1 : d2;
        int i = ((blk2 & 255) * 256 + t) * 4;
        float4 v = *(const float4*)(src + i);
        ushort4 o;
        o.x = f2bf(v.x); o.y = f2bf(v.y); o.z = f2bf(v.z); o.w = f2bf(v.w);
        *(ushort4*)(dst + i) = o;
    }
}

// ---------------- SE MLP: sigmoid scales, once per batch (grid = BB) ----------------
__global__ __launch_bounds__(256)
void se_mlp_kernel(const float* __restrict__ s_mean,
                   const float* __restrict__ fc1_w, const float* __restrict__ fc1_b,
                   const float* __restrict__ fc2_w, const float* __restrict__ fc2_b,
                   float* __restrict__ sig) {
    int b = blockIdx.x, t = threadIdx.x;
    __shared__ float sm[256];
    __shared__ float part[4][64];
    __shared__ float h1[64];
    sm[t] = s_mean[b * 256 + t];
    __syncthreads();
    int to = t & 63, g = t >> 6;
    float a = 0.f;
#pragma unroll 8
    for (int c = 0; c < 64; ++c) a += fc1_w[to * 256 + g * 64 + c] * sm[g * 64 + c];
    part[g][to] = a;
    __syncthreads();
    if (t < 64) h1[t] = fmaxf(part[0][t] + part[1][t] + part[2][t] + part[3][t] + fc1_b[t], 0.f);
    __syncthreads();
    float acc = fc2_b[t];
#pragma unroll 8
    for (int j = 0; j < 64; ++j) acc += fc2_w[t * 64 + j] * h1[j];
    sig[b * 256 + t] = 1.f / (1.f + __expf(-acc));
}

// ---- scale + transpose (+ fused qkv on ct==0 blocks); SE scales precomputed ----
__global__ __launch_bounds__(256)
void scale_transpose_qkv_kernel(const float* __restrict__ x, const float* __restrict__ sig,
                                const float* __restrict__ qW, const float* __restrict__ qB,
                                u16* __restrict__ ygt, u16* __restrict__ Qt,
                                u16* __restrict__ Kt, u16* __restrict__ Vb) {
    // grid: (16 nt, 4 ct, BB)
    int nt = blockIdx.x, ct = blockIdx.y, b = blockIdx.z;
    __shared__ float tile[64][65];
    __shared__ float ws[64 * 32];
    __shared__ float bs[64];
    __shared__ float vtile[32][64];
    __shared__ float sig_l[64];
    int t = threadIdx.x;
    const float* Xb = x + ((size_t)b * CC + ct * 64) * NP + nt * 64;
    if (t < 64) sig_l[t] = sig[b * 256 + ct * 64 + t];
    if (ct == 0) {
        for (int e = t; e < 2048; e += 256) ws[e] = qW[e];
        if (t < 64) bs[t] = qB[t];
    }
#pragma unroll
    for (int p = 0; p < 4; ++p) {
        int e = t + p * 256;
        int c = e >> 4, n4 = (e & 15) * 4;
        float4 v = *(const float4*)&Xb[(size_t)c * NP + n4];
        tile[c][n4] = v.x; tile[c][n4 + 1] = v.y; tile[c][n4 + 2] = v.z; tile[c][n4 + 3] = v.w;
    }
    __syncthreads();
    u16* Yb = ygt + ((size_t)b * NP + nt * 64) * CC + ct * 64;
#pragma unroll
    for (int p = 0; p < 4; ++p) {
        int e = t + p * 256;
        int n = e >> 4, c4 = (e & 15) * 4;
        if (ct * 64 + c4 >= 32) {
            ushort4 o;
            o.x = f2bf(tile[c4][n] * sig_l[c4]);
            o.y = f2bf(tile[c4 + 1][n] * sig_l[c4 + 1]);
            o.z = f2bf(tile[c4 + 2][n] * sig_l[c4 + 2]);
            o.w = f2bf(tile[c4 + 3][n] * sig_l[c4 + 3]);
            *(ushort4*)&Yb[(size_t)n * CC + c4] = o;
        }
    }
    if (ct == 0) {
        int nn = t & 63, g = t >> 6;
        int n = nt * 64 + nn;
        float xs[32];
#pragma unroll
        for (int c = 0; c < 32; ++c) xs[c] = tile[c][nn] * sig_l[c];
        float acc[16];
#pragma unroll
        for (int oc = 0; oc < 16; ++oc) {
            int o = g * 16 + oc;
            float a = bs[o];
#pragma unroll
            for (int c = 0; c < 32; ++c) a += ws[o * 32 + c] * xs[c];
            acc[oc] = a;
        }
        if (g == 0) {
            u16* qr = Qt + ((size_t)b * NP + n) * 32;
            ushort4 z4; z4.x = 0; z4.y = 0; z4.z = 0; z4.w = 0;
#pragma unroll
            for (int j = 0; j < 16; j += 4) {
                ushort4 o4;
                o4.x = f2bf(acc[j] * 0.25f);     o4.y = f2bf(acc[j + 1] * 0.25f);
                o4.z = f2bf(acc[j + 2] * 0.25f); o4.w = f2bf(acc[j + 3] * 0.25f);
                *(ushort4*)&qr[j] = o4;
            }
            *(ushort4*)&qr[16] = z4; *(ushort4*)&qr[20] = z4;
            *(ushort4*)&qr[24] = z4; *(ushort4*)&qr[28] = z4;
        } else if (g == 1) {
            u16* kr = Kt + ((size_t)b * NP + n) * 32;
            ushort4 z4; z4.x = 0; z4.y = 0; z4.z = 0; z4.w = 0;
#pragma unroll
            for (int j = 0; j < 16; j += 4) {
                ushort4 k4;
                k4.x = f2bf(acc[j]);     k4.y = f2bf(acc[j + 1]);
                k4.z = f2bf(acc[j + 2]); k4.w = f2bf(acc[j + 3]);
                *(ushort4*)&kr[j] = k4;
            }
            *(ushort4*)&kr[16] = z4; *(ushort4*)&kr[20] = z4;
            *(ushort4*)&kr[24] = z4; *(ushort4*)&kr[28] = z4;
        } else {
#pragma unroll
            for (int oc = 0; oc < 16; ++oc) vtile[(g - 2) * 16 + oc][nn] = acc[oc];
        }
        __syncthreads();
        for (int e = t; e < 2048; e += 256) {
            int c = e >> 6, nn2 = e & 63;
            Vb[(size_t)b * 32 * NP + (size_t)c * NP + nt * 64 + nn2] = f2bf(vtile[c][nn2]);
        }
    }
}

// ---------------- MFMA flash attention + fused proj ----------------
__global__ __launch_bounds__(256)
void attn_mfma_kernel(const u16* __restrict__ Qt, const u16* __restrict__ Kt,
                      const u16* __restrict__ Vb,
                      const float* __restrict__ proj_w, const float* __restrict__ proj_b,
                      u16* __restrict__ ygt) {
    int b = blockIdx.x & 15;
    int n0 = (blockIdx.x >> 4) * 16;
    __shared__ __align__(16) u16 P_lds[4][16][40];
    __shared__ float al_lds[4][16];
    __shared__ float sm_lds[4][16];
    __shared__ float sl_lds[4][16];
    __shared__ float O_lds[4][16][33];
    __shared__ float pw_s[32][32];
    __shared__ float pb_s[32];
    int t = threadIdx.x;
    int w = t >> 6, lane = t & 63;
    int q = lane >> 4, idx = lane & 15;

    for (int e = t; e < 1024; e += 256) pw_s[e >> 5][e & 31] = proj_w[e];
    if (t < 32) pb_s[t] = proj_b[t];
    __syncthreads();

    const u16* Qb = Qt + (size_t)b * NP * 32;
    const u16* Kb = Kt + (size_t)b * NP * 32;
    const u16* Vp = Vb + (size_t)b * 32 * NP;

    int nrow = n0 + idx;
    bf16x8 aq = *(const bf16x8*)&Qb[(size_t)nrow * 32 + q * 8];

    f32x4 O0 = {0.f, 0.f, 0.f, 0.f}, O1 = {0.f, 0.f, 0.f, 0.f};
    float m_run[4] = {-1e30f, -1e30f, -1e30f, -1e30f};
    float l_run[4] = {0.f, 0.f, 0.f, 0.f};

    int mbase = w * 256;
    for (int m0 = mbase; m0 < mbase + 256; m0 += 32) {
        bf16x8 bk0 = *(const bf16x8*)&Kb[(size_t)(m0 + idx) * 32 + q * 8];
        bf16x8 bk1 = *(const bf16x8*)&Kb[(size_t)(m0 + 16 + idx) * 32 + q * 8];
        bf16x8 va0 = *(const bf16x8*)&Vp[(size_t)idx * NP + m0 + q * 8];
        bf16x8 va1 = *(const bf16x8*)&Vp[(size_t)(16 + idx) * NP + m0 + q * 8];
        f32x4 z = {0.f, 0.f, 0.f, 0.f};
        f32x4 S0 = __builtin_amdgcn_mfma_f32_16x16x32_bf16(aq, bk0, z, 0, 0, 0);
        f32x4 S1 = __builtin_amdgcn_mfma_f32_16x16x32_bf16(aq, bk1, z, 0, 0, 0);
        float mx[4], p0[4], p1[4], alpha[4];
#pragma unroll
        for (int r = 0; r < 4; ++r) mx[r] = fmaxf(S0[r], S1[r]);
#pragma unroll
        for (int off = 1; off < 16; off <<= 1)
#pragma unroll
            for (int r = 0; r < 4; ++r) mx[r] = fmaxf(mx[r], __shfl_xor(mx[r], off, 64));
#pragma unroll
        for (int r = 0; r < 4; ++r) {
            float nm = fmaxf(m_run[r], mx[r]);
            alpha[r] = __expf(m_run[r] - nm);
            m_run[r] = nm;
            p0[r] = __expf(S0[r] - nm);
            p1[r] = __expf(S1[r] - nm);
        }
#pragma unroll
        for (int r = 0; r < 4; ++r) {
            float s = p0[r] + p1[r];
#pragma unroll
            for (int off = 1; off < 16; off <<= 1) s += __shfl_xor(s, off, 64);
            l_run[r] = l_run[r] * alpha[r] + s;
        }
#pragma unroll
        for (int r = 0; r < 4; ++r) {
            P_lds[w][q * 4 + r][idx]      = f2bf(p0[r]);
            P_lds[w][q * 4 + r][idx + 16] = f2bf(p1[r]);
        }
        if (idx == 0) {
#pragma unroll
            for (int r = 0; r < 4; ++r) al_lds[w][q * 4 + r] = alpha[r];
        }
        float an = al_lds[w][idx];
#pragma unroll
        for (int r = 0; r < 4; ++r) { O0[r] *= an; O1[r] *= an; }
        bf16x8 pf = *(const bf16x8*)&P_lds[w][idx][q * 8];
        O0 = __builtin_amdgcn_mfma_f32_16x16x32_bf16(va0, pf, O0, 0, 0, 0);
        O1 = __builtin_amdgcn_mfma_f32_16x16x32_bf16(va1, pf, O1, 0, 0, 0);
    }
    if (idx == 0) {
#pragma unroll
        for (int r = 0; r < 4; ++r) {
            sm_lds[w][q * 4 + r] = m_run[r];
            sl_lds[w][q * 4 + r] = l_run[r];
        }
    }
#pragma unroll
    for (int r = 0; r < 4; ++r) {
        O_lds[w][idx][q * 4 + r]      = O0[r];
        O_lds[w][idx][q * 4 + r + 16] = O1[r];
    }
    __syncthreads();
    if (w == 0) {
        float m0_ = sm_lds[0][idx], m1 = sm_lds[1][idx], m2 = sm_lds[2][idx], m3 = sm_lds[3][idx];
        float gm = fmaxf(fmaxf(m0_, m1), fmaxf(m2, m3));
        float e0 = __expf(m0_ - gm), e1 = __expf(m1 - gm);
        float e2 = __expf(m2 - gm), e3 = __expf(m3 - gm);
        float linv = 1.f / (sl_lds[0][idx] * e0 + sl_lds[1][idx] * e1 +
                            sl_lds[2][idx] * e2 + sl_lds[3][idx] * e3);
#pragma unroll
        for (int r = 0; r < 4; ++r) {
            int c0 = q * 4 + r;
            O_lds[0][idx][c0] = (O_lds[0][idx][c0] * e0 + O_lds[1][idx][c0] * e1 +
                                 O_lds[2][idx][c0] * e2 + O_lds[3][idx][c0] * e3) * linv;
            int c1 = c0 + 16;
            O_lds[0][idx][c1] = (O_lds[0][idx][c1] * e0 + O_lds[1][idx][c1] * e1 +
                                 O_lds[2][idx][c1] * e2 + O_lds[3][idx][c1] * e3) * linv;
        }
        float o0[4], o1[4];
#pragma unroll
        for (int r = 0; r < 4; ++r) { o0[r] = pb_s[q * 4 + r]; o1[r] = pb_s[q * 4 + r + 16]; }
#pragma unroll
        for (int c = 0; c < 32; ++c) {
            float xv = O_lds[0][idx][c];
#pragma unroll
            for (int r = 0; r < 4; ++r) {
                o0[r] += pw_s[q * 4 + r][c] * xv;
                o1[r] += pw_s[q * 4 + r + 16][c] * xv;
            }
        }
        u16* yrow = ygt + ((size_t)b * NP + n0 + idx) * CC;
        ushort4 w0, w1;
        w0.x = f2bf(o0[0]); w0.y = f2bf(o0[1]); w0.z = f2bf(o0[2]); w0.w = f2bf(o0[3]);
        w1.x = f2bf(o1[0]); w1.y = f2bf(o1[1]); w1.z = f2bf(o1[2]); w1.w = f2bf(o1[3]);
        *(ushort4*)&yrow[q * 4] = w0;
        *(ushort4*)&yrow[q * 4 + 16] = w1;
    }
}

// ---------------- Fused FFN v5: 2x reg-blocked stage1, counted-vmcnt W2 pipeline ----------------
// 64 px/block, 8 waves, grid 256. Superchunk = 256 h rows (4 iters); wave w computes h rows
// [w*32,+32) (af[2][8] in regs, halves stage1 LDS reads). Stage2: wave w owns out rows [w*32,+32),
// full k per 64-chunk (no cross-wave reduction). W2 streamed in 32 KB chunks via global_load_lds
// into a 2-buffer rotation; raw s_barrier + counted s_waitcnt keeps 2 chunk-DMAs in flight
// across barriers (vmcnt(4/20), never 0 until the last chunk).
__global__ __launch_bounds__(512, 2)
void ffn_fused_kernel(const u16* __restrict__ w1b, const u16* __restrict__ w2b,
                      const u16* __restrict__ ygt,
                      const float* __restrict__ bias1, const float* __restrict__ bias2,
                      float* __restrict__ out) {
    __shared__ __align__(16) u16 Ys[4][64][64];     // 32 KB: y tile [kb][n][64k swz]
    __shared__ __align__(16) u16 Hs[64][256];       // 32 KB: h superchunk [n][256m swz per 64-chunk]
    __shared__ __align__(16) u16 W2s[2][256][64];   // 64 KB: 2 x 32 KB W2 k-chunk buffers
    __shared__ float Bs1[1024];                     // 4 KB
    int t = threadIdx.x;
    int w = t >> 6, lane = t & 63;
    int q = lane >> 4, idx = lane & 15;
    int srow = lane >> 3;            // 0..7
    int gch = (lane & 7) ^ srow;     // pre-swizzled source chunk
    int n0 = blockIdx.x * 64;        // flat pixel base (b*1024 + n)
    int rot = blockIdx.x & 3;        // superchunk rotation (decorrelate weight-line hotspots)

#define BAR_SYNC { __builtin_amdgcn_s_barrier(); __builtin_amdgcn_sched_barrier(0); }

#define ISSUE_CHUNK(gp_, buf_)                                                            \
    {                                                                                     \
        _Pragma("unroll")                                                                 \
        for (int e = 0; e < 4; ++e) {                                                     \
            __builtin_amdgcn_global_load_lds(                                             \
                (const __attribute__((address_space(1))) void*)(w2b + (size_t)(e * 64 + w * 8 + srow) * 1024 + (gp_) * 64 + gch * 8), \
                (__attribute__((address_space(3))) void*)(&W2s[buf_][e * 64 + w * 8][0]), \
                16, 0, 0);                                                                \
        }                                                                                 \
    }

#define LOAD_AF(scp_)                                                                     \
    {                                                                                     \
        const u16* a1 = w1b + ((size_t)((scp_) * 256 + w * 32 + idx)) * CC;               \
        _Pragma("unroll")                                                                 \
        for (int i2 = 0; i2 < 2; ++i2)                                                    \
            _Pragma("unroll")                                                             \
            for (int s = 0; s < 8; ++s)                                                   \
                af[i2][s] = *(const bf16x8*)(a1 + i2 * 16 * CC + s * 32 + q * 8);         \
    }

    // ---- prologue: bias -> LDS first (its vmcnt drain happens before chunk issues) ----
    Bs1[t] = bias1[t];
    Bs1[t + 512] = bias1[t + 512];

    bf16x8 af[2][8];
    LOAD_AF(rot)                    // af for superchunk 0 (phys = rot)

#pragma unroll
    for (int e = 0; e < 4; ++e) {
        __builtin_amdgcn_global_load_lds(
            (const __attribute__((address_space(1))) void*)(ygt + (size_t)(n0 + w * 8 + srow) * CC + e * 64 + gch * 8),
            (__attribute__((address_space(3))) void*)(&Ys[e][w * 8][0]),
            16, 0, 0);
    }
    ISSUE_CHUNK(rot * 4 + 0, 0)     // logical chunk 0
    ISSUE_CHUNK(rot * 4 + 1, 1)     // logical chunk 1

    f32x4 oacc[2][4];
#pragma unroll
    for (int i2 = 0; i2 < 2; ++i2)
#pragma unroll
        for (int j = 0; j < 4; ++j) { f32x4 z = {0.f, 0.f, 0.f, 0.f}; oacc[i2][j] = z; }

    // wait: af + Ys landed; chunk0/1 (8 loads) may stay in flight
    asm volatile("s_waitcnt vmcnt(8) lgkmcnt(0)" ::: "memory");
    BAR_SYNC

    for (int sc = 0; sc < 4; ++sc) {
        int scp = (sc + rot) & 3;

        // ---- stage1: h[32m x 64n], K=256 from Ys; A in regs (af reused over j) ----
        f32x4 hacc[2][4];
#pragma unroll
        for (int i2 = 0; i2 < 2; ++i2)
#pragma unroll
            for (int j = 0; j < 4; ++j) { f32x4 z = {0.f, 0.f, 0.f, 0.f}; hacc[i2][j] = z; }
#pragma unroll
        for (int s = 0; s < 8; ++s) {
            int kb = s >> 1, h2 = s & 1;
#pragma unroll
            for (int j = 0; j < 4; ++j) {
                bf16x8 yb = *(const bf16x8*)&Ys[kb][j * 16 + idx][(((q + 4 * h2) ^ (idx & 7)) * 8)];
                hacc[0][j] = __builtin_amdgcn_mfma_f32_16x16x32_bf16(af[0][s], yb, hacc[0][j], 0, 0, 0);
                hacc[1][j] = __builtin_amdgcn_mfma_f32_16x16x32_bf16(af[1][s], yb, hacc[1][j], 0, 0, 0);
            }
        }

        // pre-pack barrier: all waves done reading Hs (prev sc stage2) before overwrite
        asm volatile("s_waitcnt lgkmcnt(0)" ::: "memory");
        BAR_SYNC

        // ---- pack: bias+relu -> bf16 -> Hs [n][256m], 64-chunk XOR swizzle ----
#pragma unroll
        for (int i2 = 0; i2 < 2; ++i2) {
            int cc2 = (2 * w + i2) >> 2;                    // 64-chunk of m
            int g8 = ((2 * w + i2) & 3) * 2 + (q >> 1);     // 8-group within chunk
            int mb = scp * 256 + w * 32 + i2 * 16 + q * 4;
            float b0 = Bs1[mb & 1023], b1v = Bs1[(mb + 1) & 1023];
            float b2v = Bs1[(mb + 2) & 1023], b3v = Bs1[(mb + 3) & 1023];
#pragma unroll
            for (int j = 0; j < 4; ++j) {
                int n = j * 16 + idx;
                uint32_t lo = (uint32_t)f2bf(fmaxf(hacc[i2][j][0] + b0, 0.f)) |
                              ((uint32_t)f2bf(fmaxf(hacc[i2][j][1] + b1v, 0.f)) << 16);
                uint32_t hi = (uint32_t)f2bf(fmaxf(hacc[i2][j][2] + b2v, 0.f)) |
                              ((uint32_t)f2bf(fmaxf(hacc[i2][j][3] + b3v, 0.f)) << 16);
                uint32_t* hp = (uint32_t*)&Hs[n][cc2 * 64 + ((g8 ^ (n & 7)) * 8) + (q & 1) * 4];
                hp[0] = lo; hp[1] = hi;
            }
        }

        // ---- 4 k-chunks of 64: stage2 with 2-buffer W2 rotation ----
#pragma unroll
        for (int c = 0; c < 4; ++c) {
            // pre-stage2: own chunk-DMA done (counted), pack/LDS visible, all waves synced
            if (c == 3) {
                if (sc == 3) { asm volatile("s_waitcnt vmcnt(0)"  ::: "memory"); }
                else         { asm volatile("s_waitcnt vmcnt(20)" ::: "memory"); }
            } else {
                asm volatile("s_waitcnt vmcnt(4)" ::: "memory");
            }
            asm volatile("s_waitcnt lgkmcnt(0)" ::: "memory");
            BAR_SYNC

            const u16 (*W2r)[64] = W2s[c & 1];
#pragma unroll
            for (int s2 = 0; s2 < 2; ++s2) {
                bf16x8 a2f[2], hb[4];
#pragma unroll
                for (int i2 = 0; i2 < 2; ++i2)
                    a2f[i2] = *(const bf16x8*)&W2r[w * 32 + i2 * 16 + idx][(((q + 4 * s2) ^ (idx & 7)) * 8)];
#pragma unroll
                for (int j = 0; j < 4; ++j)
                    hb[j] = *(const bf16x8*)&Hs[j * 16 + idx][c * 64 + (((q + 4 * s2) ^ (idx & 7)) * 8)];
#pragma unroll
                for (int i2 = 0; i2 < 2; ++i2)
#pragma unroll
                    for (int j = 0; j < 4; ++j)
                        oacc[i2][j] = __builtin_amdgcn_mfma_f32_16x16x32_bf16(a2f[i2], hb[j], oacc[i2][j], 0, 0, 0);
            }

            // post-stage2 barrier: buf (c&1) free for reuse; then prefetch issues
            asm volatile("s_waitcnt lgkmcnt(0)" ::: "memory");
            BAR_SYNC

            if (c == 2 && sc < 3) LOAD_AF((scp + 1) & 3)    // W1 frags for next superchunk
            {
                int l = sc * 4 + c;
                if (l + 2 < 16) {
                    int lp = l + 2;
                    int gp = ((((lp >> 2) + rot) & 3) << 2) | (lp & 3);
                    ISSUE_CHUNK(gp, (c & 1))                 // (l+2)&1 == c&1
                }
            }
        }
    }
#undef ISSUE_CHUNK
#undef LOAD_AF
#undef BAR_SYNC

    // ---- epilogue: fp32 out + bias2, direct stores (no reduction pass) ----
    int b = n0 >> 10, nnb = n0 & 1023;
#pragma unroll
    for (int i2 = 0; i2 < 2; ++i2) {
        int m2 = w * 32 + i2 * 16 + q * 4;
        float4 bv = *(const float4*)&bias2[m2];
#pragma unroll
        for (int j = 0; j < 4; ++j) {
            float* p = out + ((size_t)b * CC + m2) * NP + nnb + j * 16 + idx;
            f32x4 v = oacc[i2][j];
            p[0]      = v.x + bv.x;
            p[NP]     = v.y + bv.y;
            p[2 * NP] = v.z + bv.z;
            p[3 * NP] = v.w + bv.w;
        }
    }
}

extern "C" void kernel_launch(void* const* d_in, const int* in_sizes, int n_in,
                              void* d_out, int out_size, void* d_ws, size_t ws_size,
                              hipStream_t stream) {
    const float* x      = (const float*)d_in[0];
    const float* fc1_w  = (const float*)d_in[1];
    const float* fc1_b  = (const float*)d_in[2];
    const float* fc2_w  = (const float*)d_in[3];
    const float* fc2_b  = (const float*)d_in[4];
    const float* qkv_w  = (const float*)d_in[5];
    const float* qkv_b  = (const float*)d_in[6];
    const float* proj_w = (const float*)d_in[7];
    const float* proj_b = (const float*)d_in[8];
    const float* ffn1_w = (const float*)d_in[9];
    const float* ffn1_b = (const float*)d_in[10];
    const float* ffn2_w = (const float*)d_in[11];
    const float* ffn2_b = (const float*)d_in[12];
    float* out = (float*)d_out;

    // layout: [w1b 512K][w2b 512K][ygt 8M][scratch: s_mean/sig/Qt/Kt/Vb]
    u16* w1b = (u16*)d_ws;
    u16* w2b = w1b + 262144;
    u16* ygt = w2b + 262144;                         // [b*1024][256] bf16
    u16* scratch = ygt + (size_t)BB * NP * CC;
    float* s_mean = (float*)scratch;                 // 16 KB
    float* sig    = s_mean + BB * CC;                // 16 KB
    u16* Qt = (u16*)(sig + BB * CC);                 // 1 MB
    u16* Kt = Qt + (size_t)BB * NP * 32;             // 1 MB
    u16* Vb = Kt + (size_t)BB * NP * 32;             // 1 MB

    se_mean_conv_kernel<<<BB * CC + 512, 256, 0, stream>>>(x, s_mean, ffn1_w, w1b, ffn2_w, w2b);
    se_mlp_kernel<<<BB, 256, 0, stream>>>(s_mean, fc1_w, fc1_b, fc2_w, fc2_b, sig);
    scale_transpose_qkv_kernel<<<dim3(16, 4, BB), 256, 0, stream>>>(
        x, sig, qkv_w, qkv_b, ygt, Qt, Kt, Vb);
    attn_mfma_kernel<<<BB * 64, 256, 0, stream>>>(Qt, Kt, Vb, proj_w, proj_b, ygt);

    // fused FFN: out = ffn2_w @ relu(ffn1_w @ y + b1) + b2, h never touches HBM
    ffn_fused_kernel<<<256, 512, 0, stream>>>(w1b, w2b, ygt, ffn1_b, ffn2_b, out);
}